// Round 1
// baseline (460.047 us; speedup 1.0000x reference)
//
#include <hip/hip_runtime.h>
#include <hip/hip_bf16.h>

#define D_IN    2880
#define HDIM    256
#define NSPEC   4
#define NATOMS  16384
#define NSTRUCT 64
#define BM      32
#define BK      64

typedef __attribute__((ext_vector_type(4))) float f32x4;
typedef __attribute__((ext_vector_type(8))) short s16x8;

__device__ __forceinline__ short f2bf(float f) {
    return (short)__builtin_bit_cast(unsigned short, __float2bfloat16(f));
}

// in: [S][R][C] f32  ->  out: [S][C][R] bf16 (raw ushort)
template <int R, int C>
__global__ void xpose_bf16(const float* __restrict__ in, unsigned short* __restrict__ out) {
    __shared__ float tile[32][33];
    const int s  = blockIdx.z;
    const int r0 = blockIdx.x * 32;
    const int c0 = blockIdx.y * 32;
    const float* ip = in + (size_t)s * R * C;
    unsigned short* op = out + (size_t)s * C * R;
    const int tx = threadIdx.x, ty = threadIdx.y;
#pragma unroll
    for (int i = 0; i < 4; ++i)
        tile[ty + i * 8][tx] = ip[(size_t)(r0 + ty + i * 8) * C + (c0 + tx)];
    __syncthreads();
#pragma unroll
    for (int i = 0; i < 4; ++i)
        op[(size_t)(c0 + ty + i * 8) * R + (r0 + tx)] =
            (unsigned short)f2bf(tile[tx][ty + i * 8]);
}

// Fused per-species MLP: h1 = silu(X W1 + b1); h2 = silu(h1 W2 + b2);
// e = h2 . w_last + b_last + comp_w; atomicAdd into per-structure energy.
// One block = 32 atoms x full H=256. 4 waves, each 32x64 output stripe.
__global__ __launch_bounds__(256, 2)
void fused_mlp(const float* __restrict__ feat,
               const unsigned short* __restrict__ w1t,   // [S][H][D] bf16
               const float* __restrict__ b1,             // [S][H]
               const unsigned short* __restrict__ w2t,   // [S][H][H] bf16
               const float* __restrict__ b2,             // [S][H]
               const float* __restrict__ w_last,         // [S][H]
               const float* __restrict__ b_last,         // [S]
               const float* __restrict__ comp_w,         // [S]
               const int* __restrict__ sidx,             // [NATOMS]
               float* __restrict__ out)                  // [NSTRUCT]
{
    __shared__ unsigned short As[BM][BK + 8];        // 32 x 72
    __shared__ unsigned short Bs[HDIM][BK + 8];      // 256 x 72
    __shared__ unsigned short H1[BM][HDIM + 8];      // 32 x 264
    __shared__ float ered[4][BM];

    const int tid  = threadIdx.x;
    const int lane = tid & 63;
    const int wv   = tid >> 6;          // 0..3 (owns cols wv*64..wv*64+63)
    const int lrow = lane & 15;
    const int lko  = (lane >> 4) * 8;
    const int lq   = lane >> 4;
    const int g    = blockIdx.x;        // 0..511
    const int row0 = g * BM;
    const int s    = g >> 7;            // 128 tiles per species

    const float* Ag = feat + (size_t)row0 * D_IN;
    const unsigned short* B1 = w1t + (size_t)s * HDIM * D_IN;

    f32x4 acc[2][4];
#pragma unroll
    for (int i = 0; i < 2; ++i)
#pragma unroll
        for (int j = 0; j < 4; ++j)
            acc[i][j] = (f32x4){0.f, 0.f, 0.f, 0.f};

    const int ar = tid >> 3;            // 0..31 staging row (A)
    const int ac = tid & 7;             // 8-float chunk

    // ---------------- GEMM1: K = 2880, 45 iters of BK=64 ----------------
    for (int kt = 0; kt < D_IN / BK; ++kt) {
        const int k0 = kt * BK;
        {   // stage A: 32x64 fp32 -> bf16 LDS
            const float* ap = Ag + (size_t)ar * D_IN + k0 + ac * 8;
            f32x4 v0 = *(const f32x4*)ap;
            f32x4 v1 = *(const f32x4*)(ap + 4);
            s16x8 w;
            w[0] = f2bf(v0[0]); w[1] = f2bf(v0[1]); w[2] = f2bf(v0[2]); w[3] = f2bf(v0[3]);
            w[4] = f2bf(v1[0]); w[5] = f2bf(v1[1]); w[6] = f2bf(v1[2]); w[7] = f2bf(v1[3]);
            *(s16x8*)&As[ar][ac * 8] = w;
        }
        {   // stage B: 256 rows x 64 k of w1^T (bf16), row per thread
            const s16x8* bp = (const s16x8*)(B1 + (size_t)tid * D_IN + k0);
#pragma unroll
            for (int q = 0; q < 8; ++q)
                *(s16x8*)&Bs[tid][q * 8] = bp[q];
        }
        __syncthreads();
#pragma unroll
        for (int kk = 0; kk < 2; ++kk) {
            s16x8 af[2], bf_[4];
#pragma unroll
            for (int i = 0; i < 2; ++i)
                af[i] = *(const s16x8*)&As[i * 16 + lrow][kk * 32 + lko];
#pragma unroll
            for (int j = 0; j < 4; ++j)
                bf_[j] = *(const s16x8*)&Bs[wv * 64 + j * 16 + lrow][kk * 32 + lko];
#pragma unroll
            for (int i = 0; i < 2; ++i)
#pragma unroll
                for (int j = 0; j < 4; ++j)
                    acc[i][j] = __builtin_amdgcn_mfma_f32_16x16x32_bf16(
                        af[i], bf_[j], acc[i][j], 0, 0, 0);
        }
        __syncthreads();
    }

    // ---------------- bias + silu -> H1 (LDS) ----------------
    {
        const float* b1s = b1 + s * HDIM;
#pragma unroll
        for (int j = 0; j < 4; ++j) {
            const int col = wv * 64 + j * 16 + lrow;
            const float bias = b1s[col];
#pragma unroll
            for (int i = 0; i < 2; ++i)
#pragma unroll
                for (int r = 0; r < 4; ++r) {
                    float x = acc[i][j][r] + bias;
                    float sg = 1.0f / (1.0f + __expf(-x));
                    H1[i * 16 + lq * 4 + r][col] = (unsigned short)f2bf(x * sg);
                }
        }
    }
#pragma unroll
    for (int i = 0; i < 2; ++i)
#pragma unroll
        for (int j = 0; j < 4; ++j)
            acc[i][j] = (f32x4){0.f, 0.f, 0.f, 0.f};

    // ---------------- GEMM2: K = 256, 4 iters of BK=64 ----------------
    const unsigned short* B2 = w2t + (size_t)s * HDIM * HDIM;
    for (int kt = 0; kt < HDIM / BK; ++kt) {
        const int k0 = kt * BK;
        {   // stage B2 rows
            const s16x8* bp = (const s16x8*)(B2 + (size_t)tid * HDIM + k0);
#pragma unroll
            for (int q = 0; q < 8; ++q)
                *(s16x8*)&Bs[tid][q * 8] = bp[q];
        }
        __syncthreads();
#pragma unroll
        for (int kk = 0; kk < 2; ++kk) {
            s16x8 af[2], bf_[4];
#pragma unroll
            for (int i = 0; i < 2; ++i)
                af[i] = *(const s16x8*)&H1[i * 16 + lrow][k0 + kk * 32 + lko];
#pragma unroll
            for (int j = 0; j < 4; ++j)
                bf_[j] = *(const s16x8*)&Bs[wv * 64 + j * 16 + lrow][kk * 32 + lko];
#pragma unroll
            for (int i = 0; i < 2; ++i)
#pragma unroll
                for (int j = 0; j < 4; ++j)
                    acc[i][j] = __builtin_amdgcn_mfma_f32_16x16x32_bf16(
                        af[i], bf_[j], acc[i][j], 0, 0, 0);
        }
        __syncthreads();
    }

    // ---------------- epilogue: e = silu(h2) . w_last, reduce, atomic ----------------
    {
        const float* b2s = b2 + s * HDIM;
        const float* wls = w_last + s * HDIM;
        float p[8];
#pragma unroll
        for (int t = 0; t < 8; ++t) p[t] = 0.f;
#pragma unroll
        for (int j = 0; j < 4; ++j) {
            const int col = wv * 64 + j * 16 + lrow;
            const float bias = b2s[col];
            const float wl = wls[col];
#pragma unroll
            for (int i = 0; i < 2; ++i)
#pragma unroll
                for (int r = 0; r < 4; ++r) {
                    float x = acc[i][j][r] + bias;
                    float sg = 1.0f / (1.0f + __expf(-x));
                    p[i * 4 + r] += x * sg * wl;
                }
        }
        // sum over the 16 lanes (low 4 bits) that hold different cols
#pragma unroll
        for (int d = 1; d < 16; d <<= 1)
#pragma unroll
            for (int t = 0; t < 8; ++t)
                p[t] += __shfl_xor(p[t], d, 64);
        if (lrow == 0) {
#pragma unroll
            for (int i = 0; i < 2; ++i)
#pragma unroll
                for (int r = 0; r < 4; ++r)
                    ered[wv][i * 16 + lq * 4 + r] = p[i * 4 + r];
        }
        __syncthreads();
        if (tid < BM) {
            float e = ered[0][tid] + ered[1][tid] + ered[2][tid] + ered[3][tid]
                    + b_last[s] + comp_w[s];
            const int atom = row0 + tid;
            atomicAdd(&out[sidx[atom]], e);
        }
    }
}

extern "C" void kernel_launch(void* const* d_in, const int* in_sizes, int n_in,
                              void* d_out, int out_size, void* d_ws, size_t ws_size,
                              hipStream_t stream) {
    (void)in_sizes; (void)n_in; (void)out_size; (void)ws_size;
    const float* feat   = (const float*)d_in[0];
    const float* w1     = (const float*)d_in[1];
    const float* b1     = (const float*)d_in[2];
    const float* w2     = (const float*)d_in[3];
    const float* b2     = (const float*)d_in[4];
    const float* w_last = (const float*)d_in[5];
    const float* b_last = (const float*)d_in[6];
    const float* comp_w = (const float*)d_in[7];
    const int*   sidx   = (const int*)d_in[8];
    float* out = (float*)d_out;

    unsigned short* w1t = (unsigned short*)d_ws;                       // 4*256*2880 bf16
    unsigned short* w2t = (unsigned short*)((char*)d_ws + (size_t)NSPEC * HDIM * D_IN * 2);

    hipMemsetAsync(d_out, 0, NSTRUCT * sizeof(float), stream);
    xpose_bf16<D_IN, HDIM><<<dim3(D_IN / 32, HDIM / 32, NSPEC), dim3(32, 8), 0, stream>>>(w1, w1t);
    xpose_bf16<HDIM, HDIM><<<dim3(HDIM / 32, HDIM / 32, NSPEC), dim3(32, 8), 0, stream>>>(w2, w2t);
    fused_mlp<<<NATOMS / BM, 256, 0, stream>>>(feat, w1t, b1, w2t, b2,
                                               w_last, b_last, comp_w, sidx, out);
}

// Round 3
// 403.911 us; speedup vs baseline: 1.1390x; 1.1390x over previous
//
#include <hip/hip_runtime.h>
#include <hip/hip_bf16.h>

#define D_IN    2880
#define HDIM    256
#define NSPEC   4
#define NATOMS  16384
#define NSTRUCT 64
#define NT1     45     // D_IN/64
#define NT2     4      // HDIM/64
#define BM      64

typedef __attribute__((ext_vector_type(4))) float f32x4;
typedef __attribute__((ext_vector_type(8))) short s16x8;
typedef __attribute__((ext_vector_type(4))) unsigned short u16x4;

__device__ __forceinline__ short f2bf(float f) {
    return (short)__builtin_bit_cast(unsigned short, __float2bfloat16(f));
}

// Pack weights [S][RDIM][256] f32 -> MFMA-fragment-ordered bf16:
// wp[(s*(RDIM/64)+kt)*16384 + (hq*2+kk)*512 + lane*8 + e]
//   = bf16( w[s][kt*64 + kk*32 + (lane>>4)*8 + e][hq*16 + (lane&15)] )
// so a wave's B-fragment (16 cols hq, 32 k's of k-tile kt half kk) is one
// contiguous 1KB block: base + lane*16B.
template<int RDIM>
__global__ void pack_w(const float* __restrict__ w, unsigned short* __restrict__ wp) {
    __shared__ unsigned short T[64][264];
    const int kt = blockIdx.x, s = blockIdx.y;
    const int t = threadIdx.x;
    const float* src = w + ((size_t)s * RDIM + kt * 64) * HDIM;
#pragma unroll
    for (int i = 0; i < 16; ++i) {
        const int row = i * 4 + (t >> 6);
        const int c4 = (t & 63) * 4;
        f32x4 v = *(const f32x4*)(src + (size_t)row * HDIM + c4);
        u16x4 u;
        u[0] = (unsigned short)f2bf(v[0]); u[1] = (unsigned short)f2bf(v[1]);
        u[2] = (unsigned short)f2bf(v[2]); u[3] = (unsigned short)f2bf(v[3]);
        *(u16x4*)&T[row][c4] = u;
    }
    __syncthreads();
    unsigned short* dst = wp + ((size_t)s * (RDIM / 64) + kt) * 16384;
    const int l = t & 63;
#pragma unroll
    for (int it = 0; it < 8; ++it) {
        const int c = (t >> 6) + it * 4;          // 0..31  (= hq*2+kk)
        const int hq = c >> 1, kk = c & 1;
        s16x8 vv;
#pragma unroll
        for (int e = 0; e < 8; ++e)
            vv[e] = (short)T[kk * 32 + (l >> 4) * 8 + e][hq * 16 + (l & 15)];
        *(s16x8*)(dst + (size_t)c * 512 + l * 8) = vv;
    }
}

__device__ __forceinline__ int aswz(int row, int colbyte) {   // A tile: 128B rows
    return row * 128 + (colbyte ^ ((row & 7) << 4));
}
__device__ __forceinline__ int hswz(int row, int colbyte) {   // H1 tile: 512B rows
    return row * 512 + (colbyte ^ ((row & 7) << 4));
}

// 256 blocks x 512 threads. Block = 64 atoms x 256 cols, 8 waves each 32x64.
// B fragments come straight from packed global (L2-resident, XCD-pinned);
// A (features, fp32->bf16) through swizzled double-buffered LDS, 1 barrier/iter.
__global__ __launch_bounds__(512, 2)
void fused_mlp(const float* __restrict__ feat,
               const unsigned short* __restrict__ w1p,
               const float* __restrict__ b1,
               const unsigned short* __restrict__ w2p,
               const float* __restrict__ b2,
               const float* __restrict__ w_last,
               const float* __restrict__ b_last,
               const float* __restrict__ comp_w,
               const int* __restrict__ sidx,
               float* __restrict__ out)
{
    __shared__ __align__(16) char Ab[2][8192];     // 64x64 bf16, swizzled
    __shared__ __align__(16) char Hb[BM * 512];    // 64x256 bf16, swizzled
    __shared__ float ered[4][BM];

    const int tid  = threadIdx.x;
    const int lane = tid & 63;
    const int wv   = tid >> 6;            // 0..7
    const int wr   = wv >> 2, wc = wv & 3;
    const int lrow = lane & 15, lq = lane >> 4;
    const int g    = blockIdx.x;
    const int s    = (g & 7) >> 1;                       // species pinned to XCD pair
    const int mloc = ((g >> 3) << 1) | (g & 1);          // 0..63
    const int row0 = s * (NATOMS / NSPEC) + mloc * BM;

    const float* Ag = feat + (size_t)row0 * D_IN;
    const unsigned short* B1 = w1p + (size_t)s * NT1 * 16384;
    const unsigned short* B2 = w2p + (size_t)s * NT2 * 16384;

    const int ar  = tid >> 3;             // staging row 0..63
    const int acb = (tid & 7) * 16;       // staging col byte
    const int awo = aswz(ar, acb);

    f32x4 acc[2][4];
#pragma unroll
    for (int i = 0; i < 2; ++i)
#pragma unroll
        for (int j = 0; j < 4; ++j) acc[i][j] = (f32x4){0.f, 0.f, 0.f, 0.f};

    // ---- prologue: stage A(0), prefetch B(0) ----
    {
        const float* ap = Ag + (size_t)ar * D_IN + (tid & 7) * 8;
        f32x4 v0 = *(const f32x4*)ap;
        f32x4 v1 = *(const f32x4*)(ap + 4);
        s16x8 pw;
        pw[0]=f2bf(v0[0]); pw[1]=f2bf(v0[1]); pw[2]=f2bf(v0[2]); pw[3]=f2bf(v0[3]);
        pw[4]=f2bf(v1[0]); pw[5]=f2bf(v1[1]); pw[6]=f2bf(v1[2]); pw[7]=f2bf(v1[3]);
        *(s16x8*)(&Ab[0][0] + awo) = pw;
    }
    s16x8 Bf[2][4][2];
#pragma unroll
    for (int j = 0; j < 4; ++j)
#pragma unroll
        for (int kk = 0; kk < 2; ++kk)
            Bf[0][j][kk] = *(const s16x8*)(B1 + ((wc * 4 + j) * 2 + kk) * 512 + lane * 8);
    __syncthreads();

    // ---- GEMM1: 45 K-steps ----
#pragma unroll 2
    for (int kt = 0; kt < NT1; ++kt) {
        const int cb = kt & 1, nb = cb ^ 1;
        const bool hn = (kt + 1) < NT1;
        f32x4 a0, a1;
        if (hn) {
            const float* ap = Ag + (size_t)ar * D_IN + (kt + 1) * 64 + (tid & 7) * 8;
            a0 = *(const f32x4*)ap;
            a1 = *(const f32x4*)(ap + 4);
#pragma unroll
            for (int j = 0; j < 4; ++j)
#pragma unroll
                for (int kk = 0; kk < 2; ++kk)
                    Bf[nb][j][kk] = *(const s16x8*)(B1 + ((size_t)(kt + 1) * 32 + (wc * 4 + j) * 2 + kk) * 512 + lane * 8);
        }
        s16x8 af[2][2];
#pragma unroll
        for (int i = 0; i < 2; ++i)
#pragma unroll
            for (int kk = 0; kk < 2; ++kk)
                af[i][kk] = *(const s16x8*)(&Ab[cb][0] + aswz(wr * 32 + i * 16 + lrow, kk * 64 + lq * 16));
#pragma unroll
        for (int kk = 0; kk < 2; ++kk)
#pragma unroll
            for (int i = 0; i < 2; ++i)
#pragma unroll
                for (int j = 0; j < 4; ++j)
                    acc[i][j] = __builtin_amdgcn_mfma_f32_16x16x32_bf16(af[i][kk], Bf[cb][j][kk], acc[i][j], 0, 0, 0);
        if (hn) {
            s16x8 pw;
            pw[0]=f2bf(a0[0]); pw[1]=f2bf(a0[1]); pw[2]=f2bf(a0[2]); pw[3]=f2bf(a0[3]);
            pw[4]=f2bf(a1[0]); pw[5]=f2bf(a1[1]); pw[6]=f2bf(a1[2]); pw[7]=f2bf(a1[3]);
            *(s16x8*)(&Ab[nb][0] + awo) = pw;
        }
        __syncthreads();
    }

    // ---- bias + silu -> H1 (swizzled LDS) ----
    {
        const float* b1s = b1 + s * HDIM;
#pragma unroll
        for (int j = 0; j < 4; ++j) {
            const int col = wc * 64 + j * 16 + lrow;
            const float bias = b1s[col];
#pragma unroll
            for (int i = 0; i < 2; ++i)
#pragma unroll
                for (int r = 0; r < 4; ++r) {
                    float x = acc[i][j][r] + bias;
                    float sg = 1.0f / (1.0f + __expf(-x));
                    const int row = wr * 32 + i * 16 + lq * 4 + r;
                    *(unsigned short*)(&Hb[0] + hswz(row, col * 2)) = (unsigned short)f2bf(x * sg);
                }
        }
    }
#pragma unroll
    for (int i = 0; i < 2; ++i)
#pragma unroll
        for (int j = 0; j < 4; ++j) acc[i][j] = (f32x4){0.f, 0.f, 0.f, 0.f};

    // prefetch B2(0) before the barrier that publishes H1
    s16x8 B2f[2][4][2];
#pragma unroll
    for (int j = 0; j < 4; ++j)
#pragma unroll
        for (int kk = 0; kk < 2; ++kk)
            B2f[0][j][kk] = *(const s16x8*)(B2 + ((wc * 4 + j) * 2 + kk) * 512 + lane * 8);
    __syncthreads();

    // ---- GEMM2: 4 K-steps, H1 read-only, no barriers ----
#pragma unroll
    for (int kt = 0; kt < NT2; ++kt) {
        const int cb = kt & 1, nb = cb ^ 1;
        if (kt + 1 < NT2) {
#pragma unroll
            for (int j = 0; j < 4; ++j)
#pragma unroll
                for (int kk = 0; kk < 2; ++kk)
                    B2f[nb][j][kk] = *(const s16x8*)(B2 + ((size_t)(kt + 1) * 32 + (wc * 4 + j) * 2 + kk) * 512 + lane * 8);
        }
        s16x8 af[2][2];
#pragma unroll
        for (int i = 0; i < 2; ++i)
#pragma unroll
            for (int kk = 0; kk < 2; ++kk)
                af[i][kk] = *(const s16x8*)(&Hb[0] + hswz(wr * 32 + i * 16 + lrow, kt * 128 + kk * 64 + lq * 16));
#pragma unroll
        for (int kk = 0; kk < 2; ++kk)
#pragma unroll
            for (int i = 0; i < 2; ++i)
#pragma unroll
                for (int j = 0; j < 4; ++j)
                    acc[i][j] = __builtin_amdgcn_mfma_f32_16x16x32_bf16(af[i][kk], B2f[cb][j][kk], acc[i][j], 0, 0, 0);
    }

    // ---- epilogue: e = silu(h2) . w_last ; reduce ; atomic per atom ----
    {
        const float* b2s = b2 + s * HDIM;
        const float* wls = w_last + s * HDIM;
        float p[8];
#pragma unroll
        for (int t = 0; t < 8; ++t) p[t] = 0.f;
#pragma unroll
        for (int j = 0; j < 4; ++j) {
            const int col = wc * 64 + j * 16 + lrow;
            const float bias = b2s[col];
            const float wl = wls[col];
#pragma unroll
            for (int i = 0; i < 2; ++i)
#pragma unroll
                for (int r = 0; r < 4; ++r) {
                    float x = acc[i][j][r] + bias;
                    float sg = 1.0f / (1.0f + __expf(-x));
                    p[i * 4 + r] += x * sg * wl;
                }
        }
#pragma unroll
        for (int d = 1; d < 16; d <<= 1)
#pragma unroll
            for (int t = 0; t < 8; ++t)
                p[t] += __shfl_xor(p[t], d, 64);
        if (lrow == 0) {
#pragma unroll
            for (int i = 0; i < 2; ++i)
#pragma unroll
                for (int r = 0; r < 4; ++r)
                    ered[wc][wr * 32 + i * 16 + lq * 4 + r] = p[i * 4 + r];
        }
        __syncthreads();
        if (tid < BM) {
            float e = ered[0][tid] + ered[1][tid] + ered[2][tid] + ered[3][tid]
                    + b_last[s] + comp_w[s];
            atomicAdd(&out[sidx[row0 + tid]], e);
        }
    }
}

extern "C" void kernel_launch(void* const* d_in, const int* in_sizes, int n_in,
                              void* d_out, int out_size, void* d_ws, size_t ws_size,
                              hipStream_t stream) {
    (void)in_sizes; (void)n_in; (void)out_size; (void)ws_size;
    const float* feat   = (const float*)d_in[0];
    const float* w1     = (const float*)d_in[1];
    const float* b1     = (const float*)d_in[2];
    const float* w2     = (const float*)d_in[3];
    const float* b2     = (const float*)d_in[4];
    const float* w_last = (const float*)d_in[5];
    const float* b_last = (const float*)d_in[6];
    const float* comp_w = (const float*)d_in[7];
    const int*   sidx   = (const int*)d_in[8];
    float* out = (float*)d_out;

    unsigned short* w1p = (unsigned short*)d_ws;                   // 4*45*16384 shorts
    unsigned short* w2p = w1p + (size_t)NSPEC * NT1 * 16384;       // 4*4*16384 shorts

    hipMemsetAsync(d_out, 0, NSTRUCT * sizeof(float), stream);
    pack_w<D_IN><<<dim3(NT1, NSPEC), 256, 0, stream>>>(w1, w1p);
    pack_w<HDIM><<<dim3(NT2, NSPEC), 256, 0, stream>>>(w2, w2p);
    fused_mlp<<<256, 512, 0, stream>>>(feat, w1p, b1, w2p, b2,
                                       w_last, b_last, comp_w, sidx, out);
}